// Round 6
// baseline (1242.494 us; speedup 1.0000x reference)
//
#include <hip/hip_runtime.h>
#include <hip/hip_bf16.h>
#include <math.h>

#define NTOK 8192
#define DIM  768
#define HDIM 3072
#define NE   8
#define CAP  2560
#define AMAX 16384

typedef __bf16 bf16x8  __attribute__((ext_vector_type(8)));
typedef __bf16 bf16x2  __attribute__((ext_vector_type(2)));
typedef float  floatx4 __attribute__((ext_vector_type(4)));

// gelu exact via A&S 7.1.26 erf poly (|err| < 1.5e-7)
__device__ __forceinline__ float gelu_exact(float v) {
  float z = fabsf(v) * 0.7071067811865475f;
  float t = __builtin_amdgcn_rcpf(1.0f + 0.3275911f * z);
  float p = ((((1.061405429f * t - 1.453152027f) * t + 1.421413741f) * t
              - 0.284496736f) * t + 0.254829592f) * t;
  float e = 1.0f - p * __expf(-z * z);
  e = copysignf(e, v);
  return 0.5f * v * (1.0f + e);
}

// ---------------- fused weight transpose + fp32->bf16: [E][K][N] -> [E][N][K] ----------
__global__ __launch_bounds__(256) void transpose_conv2(
    const float* __restrict__ w1, const float* __restrict__ w2,
    __bf16* __restrict__ o1, __bf16* __restrict__ o2)
{
  const int which = blockIdx.z;
  const float* src = which ? w2 : w1;
  __bf16* dst = which ? o2 : o1;
  const int Kd = which ? HDIM : DIM;
  const int Nd = which ? DIM : HDIM;
  const int e = blockIdx.y;
  const int tilesK = Kd >> 6;
  const int bk = blockIdx.x % tilesK, bn = blockIdx.x / tilesK;
  __shared__ float T[64][65];
  const float* se = src + (size_t)e * Kd * Nd;
  const int k0 = bk * 64, n0 = bn * 64;
  const int tid = threadIdx.x;
#pragma unroll
  for (int it = 0; it < 16; ++it) {
    int flat = tid + it * 256;
    int kk = flat >> 6, nn = flat & 63;
    T[kk][nn] = se[(size_t)(k0 + kk) * Nd + n0 + nn];
  }
  __syncthreads();
  const int n = tid >> 2, kg = tid & 3;
  bf16x8 v0, v1;
#pragma unroll
  for (int q = 0; q < 8; ++q) v0[q] = (__bf16)T[kg * 16 + q][n];
#pragma unroll
  for (int q = 0; q < 8; ++q) v1[q] = (__bf16)T[kg * 16 + 8 + q][n];
  __bf16* de = dst + (size_t)e * Nd * Kd + (size_t)(n0 + n) * Kd + k0 + kg * 16;
  *(bf16x8*)(de) = v0;
  *(bf16x8*)(de + 8) = v1;
}

// ---------------- router: block-aggregated dispatch (1 global atomic per expert/block) --
__global__ __launch_bounds__(256) void router_kernel(
    const float* __restrict__ x, const float* __restrict__ rw,
    int* __restrict__ list_len, double* __restrict__ imp, double* __restrict__ loadacc,
    int* __restrict__ aidx, float* __restrict__ keyarr, float* __restrict__ warr)
{
  __shared__ float Wl[NE * DIM];
  __shared__ int   lcount[NE], lbase[NE];
  __shared__ int   s_e[32][2], s_pos[32][2];
  __shared__ float s_key[32][2], s_w[32][2];
  const int tid = threadIdx.x;
  for (int i = tid; i < NE * DIM; i += 256) {
    int e = i / DIM, d = i - e * DIM;
    Wl[i] = rw[d * NE + e];
  }
  if (tid < NE) lcount[tid] = 0;
  __syncthreads();
  const int wave = tid >> 6, lane = tid & 63;
  double my_imp = 0.0, my_load = 0.0;

  for (int it = 0; it < 8; ++it) {
    const int t = wave * 8 + it;
    const int n = blockIdx.x * 32 + t;
    const float* xr = x + (size_t)n * DIM;
    float part[NE];
#pragma unroll
    for (int e = 0; e < NE; ++e) part[e] = 0.f;
#pragma unroll
    for (int c = 0; c < DIM / 64; ++c) {
      float xv = xr[c * 64 + lane];
#pragma unroll
      for (int e = 0; e < NE; ++e) part[e] += xv * Wl[e * DIM + c * 64 + lane];
    }
#pragma unroll
    for (int off = 32; off > 0; off >>= 1) {
#pragma unroll
      for (int e = 0; e < NE; ++e) part[e] += __shfl_xor(part[e], off);
    }
    int e0 = 0; float v0 = part[0];
#pragma unroll
    for (int e = 1; e < NE; ++e) if (part[e] > v0) { v0 = part[e]; e0 = e; }
    int e1 = -1; float v1 = -3.4e38f;
#pragma unroll
    for (int e = 0; e < NE; ++e) if (e != e0 && part[e] > v1) { v1 = part[e]; e1 = e; }

    float pexp[NE]; float s = 0.f;
#pragma unroll
    for (int e = 0; e < NE; ++e) { pexp[e] = expf(part[e] - v0); s += pexp[e]; }
    const float inv = 1.0f / s;
    const float pr = inv;
    float w1v = 0.f;
#pragma unroll
    for (int e = 0; e < NE; ++e) if (e == e1) w1v = pexp[e] * inv;

    float myl = 0.f, mypexp = 0.f;
#pragma unroll
    for (int e = 0; e < NE; ++e) if (lane == e) { myl = part[e]; mypexp = pexp[e]; }
    if (lane < NE) {
      my_imp  += (double)(mypexp * inv);
      my_load += (double)(0.5f * erfcf((v1 - myl) * 5.656854249492380f));
    }
    if (lane == 0) {
      int p0 = atomicAdd(&lcount[e0], 1);
      int p1 = atomicAdd(&lcount[e1], 1);
      s_e[t][0] = e0; s_pos[t][0] = p0;
      s_key[t][0] = (float)(e0 * 4) - pr;
      s_w[t][0] = pr;
      s_e[t][1] = e1; s_pos[t][1] = p1;
      s_key[t][1] = (float)(e1 * 4) - (pr - 1.0f);
      s_w[t][1] = w1v;
    }
  }
  __syncthreads();
  if (tid < NE) lbase[tid] = atomicAdd(&list_len[tid], lcount[tid]);
  __syncthreads();
  if (tid < 64) {
    const int t = tid >> 1, sl = tid & 1;
    const int e = s_e[t][sl];
    const int gp = lbase[e] + s_pos[t][sl];
    const int n = blockIdx.x * 32 + t;
    aidx[e * AMAX + gp]   = n * 2 + sl;
    keyarr[e * AMAX + gp] = s_key[t][sl];
    warr[e * AMAX + gp]   = s_w[t][sl];
  }
  if (lane < NE) {
    unsafeAtomicAdd(&imp[lane], my_imp);
    unsafeAtomicAdd(&loadacc[lane], my_load);
  }
}

// ---------------- capacity keep/compact + scalar outputs -------------------------------
__global__ __launch_bounds__(256) void compact_kernel(
    const int* __restrict__ list_len, const int* __restrict__ aidx,
    const float* __restrict__ keyarr, const float* __restrict__ warr,
    int* __restrict__ dtok, float* __restrict__ dw,
    const double* __restrict__ imp, const double* __restrict__ loadacc,
    float* __restrict__ out_scalars)
{
  __shared__ float sk[6144];
  __shared__ int   sa[6144];
  const int e = blockIdx.x, tid = threadIdx.x;
  const int C = list_len[e];
  if (C <= CAP) {
    for (int t = tid; t < C; t += 256) {
      int a = aidx[e * AMAX + t];
      dtok[e * CAP + t] = a >> 1;
      dw[e * CAP + t]   = warr[e * AMAX + t];
    }
  } else {
    const bool useL = (C <= 6144);
    if (useL) {
      for (int t = tid; t < C; t += 256) { sk[t] = keyarr[e*AMAX+t]; sa[t] = aidx[e*AMAX+t]; }
      __syncthreads();
    }
    for (int t = tid; t < C; t += 256) {
      float kt = keyarr[e*AMAX+t]; int at = aidx[e*AMAX+t];
      int r = 0;
      for (int u = 0; u < C; ++u) {
        float ku = useL ? sk[u] : keyarr[e*AMAX+u];
        int   au = useL ? sa[u] : aidx[e*AMAX+u];
        if (ku < kt || (ku == kt && au < at)) ++r;
      }
      if (r < CAP) { dtok[e*CAP + r] = at >> 1; dw[e*CAP + r] = warr[e*AMAX+t]; }
    }
  }
  if (e == 0 && tid == 0) {
    double mi = 0, ml = 0;
    for (int i = 0; i < NE; ++i) { mi += imp[i]; ml += loadacc[i]; }
    mi /= NE; ml /= NE;
    double vi = 0, vl = 0;
    for (int i = 0; i < NE; ++i) {
      double di = imp[i] - mi;     vi += di * di;
      double dl = loadacc[i] - ml; vl += dl * dl;
    }
    vi /= NE; vl /= NE;
    double li = vi / (mi * mi + 1e-6), ll = vl / (ml * ml + 1e-6);
    out_scalars[0] = (float)(0.5 * (li + ll));
    int drop = 0;
    for (int i = 0; i < NE; ++i) { int c2 = list_len[i]; if (c2 > CAP) drop += c2 - CAP; }
    out_scalars[1] = (float)drop;
    for (int i = 0; i < NE; ++i) out_scalars[2 + i] = (float)list_len[i];
  }
}

// ---------------- gather kept rows into padded bf16 A buffer [E][CAP][DIM] -------------
__global__ __launch_bounds__(256) void gather_kernel(
    const float* __restrict__ x, const int* __restrict__ dtok,
    const int* __restrict__ list_len, __bf16* __restrict__ Ag)
{
  const int row  = blockIdx.x * 4 + (threadIdx.x >> 6);
  const int lane = threadIdx.x & 63;
  const int e = row / CAP, slot = row - e * CAP;
  const int kept = min(list_len[e], CAP);
  __bf16* dst = Ag + (size_t)row * DIM;
  if (slot < kept) {
    const float* srcr = x + (size_t)dtok[e * CAP + slot] * DIM;
#pragma unroll
    for (int c = 0; c < DIM / 128; ++c) {
      float2 v = *(const float2*)(srcr + c * 128 + lane * 2);
      bf16x2 o; o[0] = (__bf16)v.x; o[1] = (__bf16)v.y;
      *(bf16x2*)(dst + c * 128 + lane * 2) = o;
    }
  } else {
    bf16x2 z; z[0] = (__bf16)0.f; z[1] = (__bf16)0.f;
#pragma unroll
    for (int c = 0; c < DIM / 128; ++c) *(bf16x2*)(dst + c * 128 + lane * 2) = z;
  }
}

// ---------------- grouped GEMM: barrier-free per-wave direct-register pipeline ---------
// Each wave owns an independent 64x128 C-tile (block = 2x2 waves = 128x256).
// A/B fragments loaded straight from global in MFMA layout (k-contiguous 16B/lane:
// lane -> row lr=lane&15, k-offset lc=(lane>>4)*8), ping-pong double-buffered in
// registers with explicit next-iter prefetch. NO LDS, NO barriers in the K-loop:
// the compiler emits fine-grained vmcnt(N) on register deps, so MFMA and loads
// interleave AITER-style. e = xcd keeps each expert's B panel L2-resident.
// MODE 0 (FC1): tn = q/tilesM. MODE 1 (FC2): split-K=2, bias only at ks==0,
// atomic scatter epilogue.
template<int MODE>
__global__ __launch_bounds__(256, 2) void moe_gemm(
    const __bf16* __restrict__ Aall, const __bf16* __restrict__ BTall,
    const float* __restrict__ bias, __bf16* __restrict__ Hout,
    float* __restrict__ Out, const int* __restrict__ dtok, const float* __restrict__ dww,
    const int* __restrict__ list_len, int Kd, int Nd, int tilesM)
{
  const int i_blk = blockIdx.x;
  const int xcd = i_blk & 7, q = i_blk >> 3;
  const int e = xcd;
  const int tm = q % tilesM;
  int tn, ks, kbase, kIters;
  if (MODE == 0) {
    tn = q / tilesM; ks = 0; kbase = 0; kIters = Kd >> 5;
  } else {
    const int pr = q / tilesM;
    tn = pr % 3; ks = pr / 3; kbase = ks * (Kd >> 1); kIters = Kd >> 6;
  }

  const int kept = min(list_len[e], CAP);
  const int mUsed = (kept + 127) >> 7;
  if (tm >= mUsed) return;

  const int tid = threadIdx.x, lane = tid & 63, wave = tid >> 6;
  const int wm = wave & 1, wn = wave >> 1;
  const int m0 = tm * 128 + wm * 64;          // this wave's 64 rows
  const int n0 = tn * 256 + wn * 128;         // this wave's 128 cols

  const __bf16* Ae = Aall + (size_t)e * CAP * Kd + kbase;
  const __bf16* Be = BTall + (size_t)e * Nd * Kd + kbase;

  const int lr = lane & 15, lc = (lane >> 4) * 8;
  const __bf16* pA[4]; const __bf16* pB[8];
#pragma unroll
  for (int i = 0; i < 4; ++i) pA[i] = Ae + (size_t)(m0 + i * 16 + lr) * Kd + lc;
#pragma unroll
  for (int j = 0; j < 8; ++j) pB[j] = Be + (size_t)(n0 + j * 16 + lr) * Kd + lc;

  floatx4 acc[4][8];
#pragma unroll
  for (int i = 0; i < 4; ++i)
#pragma unroll
    for (int j = 0; j < 8; ++j) acc[i][j] = (floatx4)0.f;

  bf16x8 a0[4], b0[8], a1[4], b1[8];
  // iter 0 fragments
#pragma unroll
  for (int i = 0; i < 4; ++i) a0[i] = *(const bf16x8*)(pA[i]);
#pragma unroll
  for (int j = 0; j < 8; ++j) b0[j] = *(const bf16x8*)(pB[j]);

  // unroll-2 ping-pong; kIters is even (24 or 48)
  for (int kt = 0; kt < kIters; kt += 2) {
    const int off1 = (kt + 1) * 32;
    if (kt + 1 < kIters) {
#pragma unroll
      for (int i = 0; i < 4; ++i) a1[i] = *(const bf16x8*)(pA[i] + off1);
#pragma unroll
      for (int j = 0; j < 8; ++j) b1[j] = *(const bf16x8*)(pB[j] + off1);
    }
#pragma unroll
    for (int i = 0; i < 4; ++i)
#pragma unroll
      for (int j = 0; j < 8; ++j)
        acc[i][j] = __builtin_amdgcn_mfma_f32_16x16x32_bf16(a0[i], b0[j], acc[i][j], 0, 0, 0);

    const int off2 = (kt + 2) * 32;
    if (kt + 2 < kIters) {
#pragma unroll
      for (int i = 0; i < 4; ++i) a0[i] = *(const bf16x8*)(pA[i] + off2);
#pragma unroll
      for (int j = 0; j < 8; ++j) b0[j] = *(const bf16x8*)(pB[j] + off2);
    }
    if (kt + 1 < kIters) {
#pragma unroll
      for (int i = 0; i < 4; ++i)
#pragma unroll
        for (int j = 0; j < 8; ++j)
          acc[i][j] = __builtin_amdgcn_mfma_f32_16x16x32_bf16(a1[i], b1[j], acc[i][j], 0, 0, 0);
    }
  }

  const int quad = lane >> 4, lcol = lane & 15;
  float bcol[8];
#pragma unroll
  for (int j = 0; j < 8; ++j)
    bcol[j] = (MODE == 1 && ks == 1) ? 0.f : bias[e * Nd + n0 + j * 16 + lcol];

  if (MODE == 0) {
#pragma unroll
    for (int i = 0; i < 4; ++i) {
#pragma unroll
      for (int r = 0; r < 4; ++r) {
        const int row = m0 + i * 16 + quad * 4 + r;  // C/D: row=(l>>4)*4+reg, col=l&15
        __bf16* hrow = Hout + ((size_t)(e * CAP + row)) * Nd;
#pragma unroll
        for (int j = 0; j < 8; ++j) {
          float v = acc[i][j][r] + bcol[j];
          hrow[n0 + j * 16 + lcol] = (__bf16)gelu_exact(v);
        }
      }
    }
  } else {
#pragma unroll
    for (int i = 0; i < 4; ++i) {
#pragma unroll
      for (int r = 0; r < 4; ++r) {
        const int row = m0 + i * 16 + quad * 4 + r;
        const float w = dww[e * CAP + row];
        if (w != 0.0f) {
          const int tok = dtok[e * CAP + row];
          float* orow = Out + (size_t)tok * DIM;
#pragma unroll
          for (int j = 0; j < 8; ++j) {
            float v = w * (acc[i][j][r] + bcol[j]);
            unsafeAtomicAdd(&orow[n0 + j * 16 + lcol], v);
          }
        }
      }
    }
  }
}

extern "C" void kernel_launch(void* const* d_in, const int* in_sizes, int n_in,
                              void* d_out, int out_size, void* d_ws, size_t ws_size,
                              hipStream_t stream) {
  (void)in_sizes; (void)n_in; (void)out_size; (void)ws_size;
  const float* x  = (const float*)d_in[0];
  const float* rw = (const float*)d_in[1];
  const float* w1 = (const float*)d_in[2];
  const float* b1 = (const float*)d_in[3];
  const float* w2 = (const float*)d_in[4];
  const float* b2 = (const float*)d_in[5];
  float* out = (float*)d_out;
  char* ws = (char*)d_ws;

  int*    list_len = (int*)(ws + 0);
  double* imp      = (double*)(ws + 64);
  double* loadacc  = (double*)(ws + 128);
  int*    dtok     = (int*)(ws + 256);
  float*  dw       = (float*)(ws + 256 + 81920);
  int*    aidx     = (int*)(ws + 164096);
  float*  keyarr   = (float*)(ws + 164096 + 524288);
  float*  warr     = (float*)(ws + 164096 + 1048576);
  __bf16* W1T      = (__bf16*)(ws + 2097152);
  __bf16* W2T      = (__bf16*)(ws + 2097152 + 37748736);
  __bf16* Ag       = (__bf16*)(ws + 2097152 + 2 * 37748736);
  __bf16* hbuf     = (__bf16*)(ws + 2097152 + 2 * 37748736 + 31457280);

  hipMemsetAsync(d_out, 0, (size_t)NTOK * DIM * sizeof(float), stream);
  hipMemsetAsync(ws, 0, 164096, stream);

  transpose_conv2<<<dim3(576, 8, 2), 256, 0, stream>>>(w1, w2, W1T, W2T);
  router_kernel<<<NTOK / 32, 256, 0, stream>>>(x, rw, list_len, imp, loadacc, aidx, keyarr, warr);
  compact_kernel<<<NE, 256, 0, stream>>>(list_len, aidx, keyarr, warr, dtok, dw, imp, loadacc,
                                         out + (size_t)NTOK * DIM);
  gather_kernel<<<(NE * CAP) / 4, 256, 0, stream>>>(x, dtok, list_len, Ag);
  // FC1: 8 XCD x (20 tm x 12 tn) = 1920 blocks
  moe_gemm<0><<<NE * 20 * (HDIM / 256), 256, 0, stream>>>(
      Ag, W1T, b1, hbuf, nullptr, nullptr, nullptr, list_len, DIM, HDIM, 20);
  // FC2: 8 XCD x (20 tm x 3 tn x 2 ksplit) = 960 blocks
  moe_gemm<1><<<NE * 20 * (DIM / 256) * 2, 256, 0, stream>>>(
      hbuf, W2T, b2, nullptr, out, dtok, dw, list_len, HDIM, DIM, 20);
}

// Round 7
// 863.512 us; speedup vs baseline: 1.4389x; 1.4389x over previous
//
#include <hip/hip_runtime.h>
#include <hip/hip_bf16.h>
#include <math.h>

#define NTOK 8192
#define DIM  768
#define HDIM 3072
#define NE   8
#define CAP  2560
#define AMAX 16384

typedef __bf16 bf16x8  __attribute__((ext_vector_type(8)));
typedef __bf16 bf16x2  __attribute__((ext_vector_type(2)));
typedef float  floatx4 __attribute__((ext_vector_type(4)));

// gelu exact via A&S 7.1.26 erf poly (|err| < 1.5e-7)
__device__ __forceinline__ float gelu_exact(float v) {
  float z = fabsf(v) * 0.7071067811865475f;
  float t = __builtin_amdgcn_rcpf(1.0f + 0.3275911f * z);
  float p = ((((1.061405429f * t - 1.453152027f) * t + 1.421413741f) * t
              - 0.284496736f) * t + 0.254829592f) * t;
  float e = 1.0f - p * __expf(-z * z);
  e = copysignf(e, v);
  return 0.5f * v * (1.0f + e);
}

// ---------------- fused weight transpose + fp32->bf16: [E][K][N] -> [E][N][K] ----------
__global__ __launch_bounds__(256) void transpose_conv2(
    const float* __restrict__ w1, const float* __restrict__ w2,
    __bf16* __restrict__ o1, __bf16* __restrict__ o2)
{
  const int which = blockIdx.z;
  const float* src = which ? w2 : w1;
  __bf16* dst = which ? o2 : o1;
  const int Kd = which ? HDIM : DIM;
  const int Nd = which ? DIM : HDIM;
  const int e = blockIdx.y;
  const int tilesK = Kd >> 6;
  const int bk = blockIdx.x % tilesK, bn = blockIdx.x / tilesK;
  __shared__ float T[64][65];
  const float* se = src + (size_t)e * Kd * Nd;
  const int k0 = bk * 64, n0 = bn * 64;
  const int tid = threadIdx.x;
#pragma unroll
  for (int it = 0; it < 16; ++it) {
    int flat = tid + it * 256;
    int kk = flat >> 6, nn = flat & 63;
    T[kk][nn] = se[(size_t)(k0 + kk) * Nd + n0 + nn];
  }
  __syncthreads();
  const int n = tid >> 2, kg = tid & 3;
  bf16x8 v0, v1;
#pragma unroll
  for (int q = 0; q < 8; ++q) v0[q] = (__bf16)T[kg * 16 + q][n];
#pragma unroll
  for (int q = 0; q < 8; ++q) v1[q] = (__bf16)T[kg * 16 + 8 + q][n];
  __bf16* de = dst + (size_t)e * Nd * Kd + (size_t)(n0 + n) * Kd + k0 + kg * 16;
  *(bf16x8*)(de) = v0;
  *(bf16x8*)(de + 8) = v1;
}

// ---------------- router: block-aggregated dispatch (1 global atomic per expert/block) --
__global__ __launch_bounds__(256) void router_kernel(
    const float* __restrict__ x, const float* __restrict__ rw,
    int* __restrict__ list_len, double* __restrict__ imp, double* __restrict__ loadacc,
    int* __restrict__ aidx, float* __restrict__ keyarr, float* __restrict__ warr)
{
  __shared__ float Wl[NE * DIM];
  __shared__ int   lcount[NE], lbase[NE];
  __shared__ int   s_e[32][2], s_pos[32][2];
  __shared__ float s_key[32][2], s_w[32][2];
  const int tid = threadIdx.x;
  for (int i = tid; i < NE * DIM; i += 256) {
    int e = i / DIM, d = i - e * DIM;
    Wl[i] = rw[d * NE + e];
  }
  if (tid < NE) lcount[tid] = 0;
  __syncthreads();
  const int wave = tid >> 6, lane = tid & 63;
  double my_imp = 0.0, my_load = 0.0;

  for (int it = 0; it < 8; ++it) {
    const int t = wave * 8 + it;
    const int n = blockIdx.x * 32 + t;
    const float* xr = x + (size_t)n * DIM;
    float part[NE];
#pragma unroll
    for (int e = 0; e < NE; ++e) part[e] = 0.f;
#pragma unroll
    for (int c = 0; c < DIM / 64; ++c) {
      float xv = xr[c * 64 + lane];
#pragma unroll
      for (int e = 0; e < NE; ++e) part[e] += xv * Wl[e * DIM + c * 64 + lane];
    }
#pragma unroll
    for (int off = 32; off > 0; off >>= 1) {
#pragma unroll
      for (int e = 0; e < NE; ++e) part[e] += __shfl_xor(part[e], off);
    }
    int e0 = 0; float v0 = part[0];
#pragma unroll
    for (int e = 1; e < NE; ++e) if (part[e] > v0) { v0 = part[e]; e0 = e; }
    int e1 = -1; float v1 = -3.4e38f;
#pragma unroll
    for (int e = 0; e < NE; ++e) if (e != e0 && part[e] > v1) { v1 = part[e]; e1 = e; }

    float pexp[NE]; float s = 0.f;
#pragma unroll
    for (int e = 0; e < NE; ++e) { pexp[e] = expf(part[e] - v0); s += pexp[e]; }
    const float inv = 1.0f / s;
    const float pr = inv;
    float w1v = 0.f;
#pragma unroll
    for (int e = 0; e < NE; ++e) if (e == e1) w1v = pexp[e] * inv;

    float myl = 0.f, mypexp = 0.f;
#pragma unroll
    for (int e = 0; e < NE; ++e) if (lane == e) { myl = part[e]; mypexp = pexp[e]; }
    if (lane < NE) {
      my_imp  += (double)(mypexp * inv);
      my_load += (double)(0.5f * erfcf((v1 - myl) * 5.656854249492380f));
    }
    if (lane == 0) {
      int p0 = atomicAdd(&lcount[e0], 1);
      int p1 = atomicAdd(&lcount[e1], 1);
      s_e[t][0] = e0; s_pos[t][0] = p0;
      s_key[t][0] = (float)(e0 * 4) - pr;
      s_w[t][0] = pr;
      s_e[t][1] = e1; s_pos[t][1] = p1;
      s_key[t][1] = (float)(e1 * 4) - (pr - 1.0f);
      s_w[t][1] = w1v;
    }
  }
  __syncthreads();
  if (tid < NE) lbase[tid] = atomicAdd(&list_len[tid], lcount[tid]);
  __syncthreads();
  if (tid < 64) {
    const int t = tid >> 1, sl = tid & 1;
    const int e = s_e[t][sl];
    const int gp = lbase[e] + s_pos[t][sl];
    const int n = blockIdx.x * 32 + t;
    aidx[e * AMAX + gp]   = n * 2 + sl;
    keyarr[e * AMAX + gp] = s_key[t][sl];
    warr[e * AMAX + gp]   = s_w[t][sl];
  }
  if (lane < NE) {
    unsafeAtomicAdd(&imp[lane], my_imp);
    unsafeAtomicAdd(&loadacc[lane], my_load);
  }
}

// ---------------- capacity keep/compact + scalar outputs -------------------------------
__global__ __launch_bounds__(256) void compact_kernel(
    const int* __restrict__ list_len, const int* __restrict__ aidx,
    const float* __restrict__ keyarr, const float* __restrict__ warr,
    int* __restrict__ dtok, float* __restrict__ dw,
    const double* __restrict__ imp, const double* __restrict__ loadacc,
    float* __restrict__ out_scalars)
{
  __shared__ float sk[6144];
  __shared__ int   sa[6144];
  const int e = blockIdx.x, tid = threadIdx.x;
  const int C = list_len[e];
  if (C <= CAP) {
    for (int t = tid; t < C; t += 256) {
      int a = aidx[e * AMAX + t];
      dtok[e * CAP + t] = a >> 1;
      dw[e * CAP + t]   = warr[e * AMAX + t];
    }
  } else {
    const bool useL = (C <= 6144);
    if (useL) {
      for (int t = tid; t < C; t += 256) { sk[t] = keyarr[e*AMAX+t]; sa[t] = aidx[e*AMAX+t]; }
      __syncthreads();
    }
    for (int t = tid; t < C; t += 256) {
      float kt = keyarr[e*AMAX+t]; int at = aidx[e*AMAX+t];
      int r = 0;
      for (int u = 0; u < C; ++u) {
        float ku = useL ? sk[u] : keyarr[e*AMAX+u];
        int   au = useL ? sa[u] : aidx[e*AMAX+u];
        if (ku < kt || (ku == kt && au < at)) ++r;
      }
      if (r < CAP) { dtok[e*CAP + r] = at >> 1; dw[e*CAP + r] = warr[e*AMAX+t]; }
    }
  }
  if (e == 0 && tid == 0) {
    double mi = 0, ml = 0;
    for (int i = 0; i < NE; ++i) { mi += imp[i]; ml += loadacc[i]; }
    mi /= NE; ml /= NE;
    double vi = 0, vl = 0;
    for (int i = 0; i < NE; ++i) {
      double di = imp[i] - mi;     vi += di * di;
      double dl = loadacc[i] - ml; vl += dl * dl;
    }
    vi /= NE; vl /= NE;
    double li = vi / (mi * mi + 1e-6), ll = vl / (ml * ml + 1e-6);
    out_scalars[0] = (float)(0.5 * (li + ll));
    int drop = 0;
    for (int i = 0; i < NE; ++i) { int c2 = list_len[i]; if (c2 > CAP) drop += c2 - CAP; }
    out_scalars[1] = (float)drop;
    for (int i = 0; i < NE; ++i) out_scalars[2 + i] = (float)list_len[i];
  }
}

// ---------------- gather kept rows into padded bf16 A buffer [E][CAP][DIM] -------------
__global__ __launch_bounds__(256) void gather_kernel(
    const float* __restrict__ x, const int* __restrict__ dtok,
    const int* __restrict__ list_len, __bf16* __restrict__ Ag)
{
  const int row  = blockIdx.x * 4 + (threadIdx.x >> 6);
  const int lane = threadIdx.x & 63;
  const int e = row / CAP, slot = row - e * CAP;
  const int kept = min(list_len[e], CAP);
  __bf16* dst = Ag + (size_t)row * DIM;
  if (slot < kept) {
    const float* srcr = x + (size_t)dtok[e * CAP + slot] * DIM;
#pragma unroll
    for (int c = 0; c < DIM / 128; ++c) {
      float2 v = *(const float2*)(srcr + c * 128 + lane * 2);
      bf16x2 o; o[0] = (__bf16)v.x; o[1] = (__bf16)v.y;
      *(bf16x2*)(dst + c * 128 + lane * 2) = o;
    }
  } else {
    bf16x2 z; z[0] = (__bf16)0.f; z[1] = (__bf16)0.f;
#pragma unroll
    for (int c = 0; c < DIM / 128; ++c) *(bf16x2*)(dst + c * 128 + lane * 2) = z;
  }
}

// ---------------- grouped GEMM: barrier-free per-wave direct-register pipeline ---------
// Each wave owns an independent 64x128 C-tile (block = 2x2 waves = 128x256).
// A/B fragments loaded straight from global in MFMA layout (k-contiguous 16B/lane).
// SINGLE-buffered fragments (R6's double-buffer spilled: 96 extra VGPRs -> 540MB
// scratch traffic). Register budget: acc 128 AGPR + frags 48 VGPR + 12 ptrs ~24
// + misc < 128 arch VGPRs -> no spill. K-loop unrolling disabled so the compiler
// cannot rotate a second fragment set back in. No LDS, no barriers: compiler
// emits fine-grained vmcnt on register deps; 2 blocks/CU stagger loads vs MFMA.
// e = xcd keeps each expert's B panel (4.7MB) ~L2-resident per XCD.
template<int MODE>
__global__ __launch_bounds__(256, 2) void moe_gemm(
    const __bf16* __restrict__ Aall, const __bf16* __restrict__ BTall,
    const float* __restrict__ bias, __bf16* __restrict__ Hout,
    float* __restrict__ Out, const int* __restrict__ dtok, const float* __restrict__ dww,
    const int* __restrict__ list_len, int Kd, int Nd, int tilesM)
{
  const int i_blk = blockIdx.x;
  const int xcd = i_blk & 7, q = i_blk >> 3;
  const int e = xcd;
  const int tm = q % tilesM;
  int tn, ks, kbase, kIters;
  if (MODE == 0) {
    tn = q / tilesM; ks = 0; kbase = 0; kIters = Kd >> 5;
  } else {
    const int pr = q / tilesM;
    tn = pr % 3; ks = pr / 3; kbase = ks * (Kd >> 1); kIters = Kd >> 6;
  }

  const int kept = min(list_len[e], CAP);
  const int mUsed = (kept + 127) >> 7;
  if (tm >= mUsed) return;

  const int tid = threadIdx.x, lane = tid & 63, wave = tid >> 6;
  const int wm = wave & 1, wn = wave >> 1;
  const int m0 = tm * 128 + wm * 64;          // this wave's 64 rows
  const int n0 = tn * 256 + wn * 128;         // this wave's 128 cols

  const __bf16* Ae = Aall + (size_t)e * CAP * Kd + kbase;
  const __bf16* Be = BTall + (size_t)e * Nd * Kd + kbase;

  const int lr = lane & 15, lc = (lane >> 4) * 8;
  const __bf16* pA[4]; const __bf16* pB[8];
#pragma unroll
  for (int i = 0; i < 4; ++i) pA[i] = Ae + (size_t)(m0 + i * 16 + lr) * Kd + lc;
#pragma unroll
  for (int j = 0; j < 8; ++j) pB[j] = Be + (size_t)(n0 + j * 16 + lr) * Kd + lc;

  floatx4 acc[4][8];
#pragma unroll
  for (int i = 0; i < 4; ++i)
#pragma unroll
    for (int j = 0; j < 8; ++j) acc[i][j] = (floatx4)0.f;

#pragma clang loop unroll(disable)
  for (int kt = 0; kt < kIters; ++kt) {
    const int off = kt * 32;
    bf16x8 a[4], b[8];
#pragma unroll
    for (int i = 0; i < 4; ++i) a[i] = *(const bf16x8*)(pA[i] + off);
#pragma unroll
    for (int j = 0; j < 8; ++j) b[j] = *(const bf16x8*)(pB[j] + off);
#pragma unroll
    for (int i = 0; i < 4; ++i)
#pragma unroll
      for (int j = 0; j < 8; ++j)
        acc[i][j] = __builtin_amdgcn_mfma_f32_16x16x32_bf16(a[i], b[j], acc[i][j], 0, 0, 0);
  }

  const int quad = lane >> 4, lcol = lane & 15;
  float bcol[8];
#pragma unroll
  for (int j = 0; j < 8; ++j)
    bcol[j] = (MODE == 1 && ks == 1) ? 0.f : bias[e * Nd + n0 + j * 16 + lcol];

  if (MODE == 0) {
#pragma unroll
    for (int i = 0; i < 4; ++i) {
#pragma unroll
      for (int r = 0; r < 4; ++r) {
        const int row = m0 + i * 16 + quad * 4 + r;  // C/D: row=(l>>4)*4+reg, col=l&15
        __bf16* hrow = Hout + ((size_t)(e * CAP + row)) * Nd;
#pragma unroll
        for (int j = 0; j < 8; ++j) {
          float v = acc[i][j][r] + bcol[j];
          hrow[n0 + j * 16 + lcol] = (__bf16)gelu_exact(v);
        }
      }
    }
  } else {
#pragma unroll
    for (int i = 0; i < 4; ++i) {
#pragma unroll
      for (int r = 0; r < 4; ++r) {
        const int row = m0 + i * 16 + quad * 4 + r;
        const float w = dww[e * CAP + row];
        if (w != 0.0f) {
          const int tok = dtok[e * CAP + row];
          float* orow = Out + (size_t)tok * DIM;
#pragma unroll
          for (int j = 0; j < 8; ++j) {
            float v = w * (acc[i][j][r] + bcol[j]);
            unsafeAtomicAdd(&orow[n0 + j * 16 + lcol], v);
          }
        }
      }
    }
  }
}

extern "C" void kernel_launch(void* const* d_in, const int* in_sizes, int n_in,
                              void* d_out, int out_size, void* d_ws, size_t ws_size,
                              hipStream_t stream) {
  (void)in_sizes; (void)n_in; (void)out_size; (void)ws_size;
  const float* x  = (const float*)d_in[0];
  const float* rw = (const float*)d_in[1];
  const float* w1 = (const float*)d_in[2];
  const float* b1 = (const float*)d_in[3];
  const float* w2 = (const float*)d_in[4];
  const float* b2 = (const float*)d_in[5];
  float* out = (float*)d_out;
  char* ws = (char*)d_ws;

  int*    list_len = (int*)(ws + 0);
  double* imp      = (double*)(ws + 64);
  double* loadacc  = (double*)(ws + 128);
  int*    dtok     = (int*)(ws + 256);
  float*  dw       = (float*)(ws + 256 + 81920);
  int*    aidx     = (int*)(ws + 164096);
  float*  keyarr   = (float*)(ws + 164096 + 524288);
  float*  warr     = (float*)(ws + 164096 + 1048576);
  __bf16* W1T      = (__bf16*)(ws + 2097152);
  __bf16* W2T      = (__bf16*)(ws + 2097152 + 37748736);
  __bf16* Ag       = (__bf16*)(ws + 2097152 + 2 * 37748736);
  __bf16* hbuf     = (__bf16*)(ws + 2097152 + 2 * 37748736 + 31457280);

  hipMemsetAsync(d_out, 0, (size_t)NTOK * DIM * sizeof(float), stream);
  hipMemsetAsync(ws, 0, 164096, stream);

  transpose_conv2<<<dim3(576, 8, 2), 256, 0, stream>>>(w1, w2, W1T, W2T);
  router_kernel<<<NTOK / 32, 256, 0, stream>>>(x, rw, list_len, imp, loadacc, aidx, keyarr, warr);
  compact_kernel<<<NE, 256, 0, stream>>>(list_len, aidx, keyarr, warr, dtok, dw, imp, loadacc,
                                         out + (size_t)NTOK * DIM);
  gather_kernel<<<(NE * CAP) / 4, 256, 0, stream>>>(x, dtok, list_len, Ag);
  // FC1: 8 XCD x (20 tm x 12 tn) = 1920 blocks
  moe_gemm<0><<<NE * 20 * (HDIM / 256), 256, 0, stream>>>(
      Ag, W1T, b1, hbuf, nullptr, nullptr, nullptr, list_len, DIM, HDIM, 20);
  // FC2: 8 XCD x (20 tm x 3 tn x 2 ksplit) = 960 blocks
  moe_gemm<1><<<NE * 20 * (DIM / 256) * 2, 256, 0, stream>>>(
      hbuf, W2T, b2, nullptr, out, dtok, dw, list_len, HDIM, DIM, 20);
}